// Round 12
// baseline (227.795 us; speedup 1.0000x reference)
//
#include <hip/hip_runtime.h>
#include <hip/hip_bf16.h>

#define HID 128
#define BSH 7            // bucket = 128 consecutive dst nodes
#define CSRCAP 4096      // per-bucket edge capacity for LDS sort
#define PCHUNK 4096      // edges per partition block
#define HCHUNK 16384     // edges per bucket-hist block

typedef __attribute__((ext_vector_type(8))) short short8v;
typedef __attribute__((ext_vector_type(4))) float f32x4;
typedef __attribute__((ext_vector_type(2))) float f32x2;

#if defined(__has_builtin)
#if __has_builtin(__builtin_amdgcn_cvt_f32_fp8) && __has_builtin(__builtin_amdgcn_cvt_pk_fp8_f32)
#define HAVE_HW_FP8 1
#endif
#if __has_builtin(__builtin_amdgcn_cvt_pk_f32_fp8)
#define HAVE_HW_FP8_PK 1
#endif
#endif

__device__ __forceinline__ float4 f4fma(float a, float4 x, float4 y) {
    y.x += a * x.x; y.y += a * x.y; y.z += a * x.z; y.w += a * x.w; return y;
}
__device__ __forceinline__ unsigned f2bf2(float lo, float hi) {
    unsigned ul = __float_as_uint(lo), uh = __float_as_uint(hi);
    ul = (ul + 0x7FFF + ((ul >> 16) & 1)) >> 16;
    uh = (uh + 0x7FFF + ((uh >> 16) & 1)) & 0xFFFF0000u;
    return ul | uh;
}
__device__ __forceinline__ unsigned short f2bf1(float v) {
    unsigned u = __float_as_uint(v);
    u = (u + 0x7FFF + ((u >> 16) & 1)) >> 16;
    return (unsigned short)u;
}
__device__ __forceinline__ float bflo(unsigned u) { return __uint_as_float(u << 16); }
__device__ __forceinline__ float bfhi(unsigned u) { return __uint_as_float(u & 0xFFFF0000u); }
__device__ __forceinline__ float bf2f(unsigned short b) {
    return __uint_as_float(((unsigned)b) << 16);
}
__device__ __forceinline__ short8v zero8() {
    short8v z = {0, 0, 0, 0, 0, 0, 0, 0};
    return z;
}

// ---- fp8 e4m3 (values >= 0 only) ----
#ifndef HAVE_HW_FP8
__device__ __forceinline__ unsigned fp8enc_pos(float a) {
    if (a >= 448.f) return 0x7Eu;
    if (a < 0.0009765625f) return 0u;
    unsigned b = __float_as_uint(a);
    int e = (int)(b >> 23) - 127;
    if (e >= -6) {
        unsigned r = b + 0x7FFFFu + ((b >> 20) & 1u);
        e = (int)(r >> 23) - 127;
        unsigned m = (r >> 20) & 7u;
        return ((unsigned)(e + 7) << 3) | m;
    } else {
        int m = (int)(a * 512.f + 0.5f);
        return (unsigned)m;
    }
}
__device__ __forceinline__ float fp8dec1(unsigned u7) {
    float fn = __uint_as_float((u7 + 0x3C0u) << 20);
    float fs = (float)u7 * 0.001953125f;
    return u7 >= 8 ? fn : fs;
}
#endif

__device__ __forceinline__ unsigned char enc1(float a) {
#ifdef HAVE_HW_FP8
    return (unsigned char)(__builtin_amdgcn_cvt_pk_fp8_f32(a, 0.f, 0, false) & 0xff);
#else
    return (unsigned char)fp8enc_pos(a);
#endif
}

// decode 16 fp8 -> 8 packed float2
__device__ __forceinline__ void dec16p(uint4 u, f32x2* v) {
#ifdef HAVE_HW_FP8_PK
    v[0] = __builtin_amdgcn_cvt_pk_f32_fp8((int)u.x, false);
    v[1] = __builtin_amdgcn_cvt_pk_f32_fp8((int)u.x, true);
    v[2] = __builtin_amdgcn_cvt_pk_f32_fp8((int)u.y, false);
    v[3] = __builtin_amdgcn_cvt_pk_f32_fp8((int)u.y, true);
    v[4] = __builtin_amdgcn_cvt_pk_f32_fp8((int)u.z, false);
    v[5] = __builtin_amdgcn_cvt_pk_f32_fp8((int)u.z, true);
    v[6] = __builtin_amdgcn_cvt_pk_f32_fp8((int)u.w, false);
    v[7] = __builtin_amdgcn_cvt_pk_f32_fp8((int)u.w, true);
#else
    unsigned w[4] = {u.x, u.y, u.z, u.w};
    #pragma unroll
    for (int k = 0; k < 4; ++k) {
        f32x2 a, b;
        a.x = fp8dec1(w[k] & 0xffu);         a.y = fp8dec1((w[k] >> 8) & 0xffu);
        b.x = fp8dec1((w[k] >> 16) & 0xffu); b.y = fp8dec1(w[k] >> 24);
        v[2 * k] = a; v[2 * k + 1] = b;
    }
#endif
}

// ---------------- bucket histogram + fused scan (last block) ----------------
__global__ __launch_bounds__(256) void k_bhist(const int* __restrict__ d1, int e1,
        const int* __restrict__ d2, int e2, int base2,
        int* __restrict__ bktcnt, int* __restrict__ bofs, int* __restrict__ bcur,
        int* __restrict__ done, int nblocks, long etot) {
    __shared__ int hist[1024];
    __shared__ int ps[256];
    __shared__ int lastflag;
    int tid = threadIdx.x;
    for (int b = tid; b < 1024; b += 256) hist[b] = 0;
    __syncthreads();
    long start = (long)blockIdx.x * HCHUNK;
    long end = start + HCHUNK; if (end > etot) end = etot;
    for (long i = start + tid; i < end; i += 256) {
        int d = (i < e1) ? d1[i] : d2[i - e1] + base2;
        atomicAdd(&hist[d >> BSH], 1);
    }
    __syncthreads();
    for (int b = tid; b < 1024; b += 256)
        if (hist[b]) atomicAdd(&bktcnt[b], hist[b]);
    __threadfence();
    if (tid == 0) lastflag = (atomicAdd(done, 1) == nblocks - 1);
    __syncthreads();
    if (!lastflag) return;
    __threadfence();
    int b4 = tid * 4;
    int h0 = bktcnt[b4], h1 = bktcnt[b4 + 1], h2 = bktcnt[b4 + 2], h3 = bktcnt[b4 + 3];
    int sum = h0 + h1 + h2 + h3;
    ps[tid] = sum; __syncthreads();
    for (int o = 1; o < 256; o <<= 1) {
        int v = (tid >= o) ? ps[tid - o] : 0;
        __syncthreads();
        ps[tid] += v;
        __syncthreads();
    }
    int ex = ps[tid] - sum;
    bofs[b4] = ex; bcur[b4] = ex;
    bofs[b4 + 1] = ex + h0; bcur[b4 + 1] = ex + h0;
    bofs[b4 + 2] = ex + h0 + h1; bcur[b4 + 2] = ex + h0 + h1;
    bofs[b4 + 3] = ex + h0 + h1 + h2; bcur[b4 + 3] = ex + h0 + h1 + h2;
    if (tid == 255) bofs[1024] = ps[255];
}

// ---------------- partition edges into bucket-grouped order (packed src<<7|dloc) ----------------
__global__ __launch_bounds__(256) void k_part(
        const int* __restrict__ s1, const int* __restrict__ d1, int e1,
        const int* __restrict__ s2, const int* __restrict__ d2, int e2, int base2,
        int* __restrict__ bcur, int* __restrict__ pedge, int nb, long etot) {
    __shared__ int hist[1024];
    __shared__ int lofs[1024];
    __shared__ int gb[1024];
    __shared__ int ps[256];
    __shared__ int stage[PCHUNK];
    __shared__ unsigned short sbk[PCHUNK];
    int tid = threadIdx.x;
    long cbase = (long)blockIdx.x * PCHUNK;
    int cnt = (int)((etot - cbase) < PCHUNK ? (etot - cbase) : PCHUNK);
    for (int b = tid; b < 1024; b += 256) hist[b] = 0;
    __syncthreads();
    for (int i = tid; i < cnt; i += 256) {
        long e = cbase + i;
        int d = (e < e1) ? d1[e] : d2[e - e1] + base2;
        atomicAdd(&hist[d >> BSH], 1);
    }
    __syncthreads();
    int h0 = hist[tid * 4], h1 = hist[tid * 4 + 1], h2 = hist[tid * 4 + 2], h3 = hist[tid * 4 + 3];
    int sum = h0 + h1 + h2 + h3;
    ps[tid] = sum; __syncthreads();
    for (int o = 1; o < 256; o <<= 1) {
        int v = (tid >= o) ? ps[tid - o] : 0;
        __syncthreads();
        ps[tid] += v;
        __syncthreads();
    }
    int ex = ps[tid] - sum;
    lofs[tid * 4] = ex; lofs[tid * 4 + 1] = ex + h0;
    lofs[tid * 4 + 2] = ex + h0 + h1; lofs[tid * 4 + 3] = ex + h0 + h1 + h2;
    __syncthreads();
    for (int b = tid; b < nb; b += 256) {
        int c = hist[b];
        gb[b] = c ? atomicAdd(&bcur[b], c) : 0;
    }
    __syncthreads();
    for (int b = tid; b < 1024; b += 256) hist[b] = 0;
    __syncthreads();
    for (int i = tid; i < cnt; i += 256) {
        long e = cbase + i;
        int s, d;
        if (e < e1) { s = s1[e]; d = d1[e]; }
        else { s = s2[e - e1] + base2; d = d2[e - e1] + base2; }
        int b = d >> BSH;
        int p = lofs[b] + atomicAdd(&hist[b], 1);
        stage[p] = (s << BSH) | (d & ((1 << BSH) - 1));
        sbk[p] = (unsigned short)b;
    }
    __syncthreads();
    for (int i = tid; i < cnt; i += 256) {
        int b = sbk[i];
        pedge[gb[b] + (i - lofs[b])] = stage[i];
    }
}

// ---------------- per-bucket sort -> src CSR + deg/offs/dinv + node records ----------------
__global__ __launch_bounds__(256) void k_csr(const int* __restrict__ pe,
        const int* __restrict__ bofs, int* __restrict__ csrs,
        int* __restrict__ deg, int* __restrict__ offs, float* __restrict__ dinv,
        const int* __restrict__ res1, const float* __restrict__ pos1,
        const int* __restrict__ res2, const float* __restrict__ pos2,
        int np, int np64, uint4* __restrict__ nrec, int n,
        int* __restrict__ bktcnt, int* __restrict__ done) {
    __shared__ int lofs2[128];
    __shared__ int lcnt[128];
    __shared__ int lcur[128];
    __shared__ int sc[128];
    __shared__ int ss[CSRCAP];
    int b = blockIdx.x, tid = threadIdx.x;
    int n0 = b << BSH;
    int nn = (n - n0) < 128 ? (n - n0) : 128;
    if (tid < 128) { lcnt[tid] = 0; lcur[tid] = 0; }
    __syncthreads();
    int base = bofs[b], total = bofs[b + 1] - base;
    for (int i = tid; i < total; i += 256)
        atomicAdd(&lcnt[pe[base + i] & ((1 << BSH) - 1)], 1);
    __syncthreads();
    int v = 0;
    if (tid < 128) { v = lcnt[tid]; sc[tid] = v; }
    __syncthreads();
    for (int o = 1; o < 128; o <<= 1) {
        int t = 0;
        if (tid < 128 && tid >= o) t = sc[tid - o];
        __syncthreads();
        if (tid < 128) sc[tid] += t;
        __syncthreads();
    }
    if (tid < 128) lofs2[tid] = sc[tid] - v;
    if (tid < nn) {
        int node = n0 + tid;
        offs[node] = base + sc[tid] - v;
        deg[node] = v;
        float dv = rsqrtf((float)(v + 1)); // +1 self loop
        dinv[node] = dv;
        const int* res = 0; const float* pos = 0; int bseg = 0; bool valid = false;
        if (node < np) { res = res1; pos = pos1; bseg = 0; valid = true; }
        else if (node >= np64) { res = res2; pos = pos2; bseg = np64; valid = true; }
        if (valid) {
            int lg = node - bseg;
            uint4 rr;
            rr.x = __float_as_uint(dv);
            rr.y = (unsigned)res[lg] | ((unsigned)f2bf1(pos[lg * 3 + 0]) << 16);
            rr.z = (unsigned)f2bf1(pos[lg * 3 + 1]) | ((unsigned)f2bf1(pos[lg * 3 + 2]) << 16);
            rr.w = 0;
            nrec[node] = rr;
        }
    }
    __syncthreads();
    if (total <= CSRCAP) {
        for (int i = tid; i < total; i += 256) {
            int e = pe[base + i];
            int ln = e & ((1 << BSH) - 1);
            int pos_ = lofs2[ln] + atomicAdd(&lcur[ln], 1);
            ss[pos_] = e >> BSH;
        }
        __syncthreads();
        for (int i = tid; i < total; i += 256) csrs[base + i] = ss[i];
    } else {
        for (int i = tid; i < total; i += 256) {
            int e = pe[base + i];
            int ln = e & ((1 << BSH) - 1);
            int pos_ = lofs2[ln] + atomicAdd(&lcur[ln], 1);
            csrs[base + pos_] = e >> BSH;
        }
    }
    if (b == 0) {  // re-zero bucket counters for the next run in this call
        for (int i = tid; i < 1024; i += 256) bktcnt[i] = 0;
        if (tid == 0) *done = 0;
    }
}

// ---------------- layer 1: compact 23-dim aggregation -> x23[ntot][32] bf16 ----------------
__global__ __launch_bounds__(256) void k_agg23c(
        const uint4* __restrict__ nrec, const int* __restrict__ offs,
        const int* __restrict__ deg, const int* __restrict__ csrs,
        int np, int np64, int nm, unsigned short* __restrict__ x23) {
    __shared__ float aggL[8][2][24];
    int grp = threadIdx.x >> 5, lane = threadIdx.x & 31;
    int g = blockIdx.x * 8 + grp;
    int ntot = np64 + nm;
    if (g >= ntot) return;
    bool valid = (g < np) || (g >= np64);
    if (!valid) {
        if (lane < 16) ((unsigned*)x23)[(size_t)g * 16 + lane] = 0;
        return;
    }
    int hf = lane >> 4;
    if (lane < 20) { aggL[grp][0][lane] = 0.f; aggL[grp][1][lane] = 0.f; }
    float sx = 0.f, sy = 0.f, sz = 0.f;
    int s0 = offs[g], m = deg[g];
    for (int i = lane; i < m; i += 32) {
        int s = csrs[s0 + i];
        uint4 r = nrec[s];                   // 16B gather, L2-resident
        float dv = __uint_as_float(r.x);
        int rs = (int)(r.y & 0xffffu);
        atomicAdd(&aggL[grp][hf][rs], dv);   // halved contention
        sx += dv * bfhi(r.y); sy += dv * bflo(r.z); sz += dv * bfhi(r.z);
    }
    uint4 sr = nrec[g];
    float dd = __uint_as_float(sr.x);
    if (lane == 0) atomicAdd(&aggL[grp][0][(int)(sr.y & 0xffffu)], dd);
    #pragma unroll
    for (int o = 1; o < 32; o <<= 1) {
        sx += __shfl_xor(sx, o, 32);
        sy += __shfl_xor(sy, o, 32);
        sz += __shfl_xor(sz, o, 32);
    }
    sx += dd * bfhi(sr.y); sy += dd * bflo(sr.z); sz += dd * bfhi(sr.z);
    float val = 0.f;
    if (lane < 20) val = aggL[grp][0][lane] + aggL[grp][1][lane];
    else if (lane == 20) val = sx;
    else if (lane == 21) val = sy;
    else if (lane == 22) val = sz;
    x23[(size_t)g * 32 + lane] = f2bf1(dd * val);
}

// ---------------- GEMM1 (K=32): hb8 = fp8(16*dinv*relu(x23 @ W1 + b1)) ----------------
__global__ __launch_bounds__(256) void k_gemm1(const unsigned short* __restrict__ A,
        const unsigned short* __restrict__ Bt1, const unsigned short* __restrict__ Bt2,
        const float* __restrict__ b1a, const float* __restrict__ b1b,
        const float* __restrict__ dinv,
        int nb1, int np64, int ntot, unsigned* __restrict__ hb8) {
    __shared__ unsigned char stb[64][144];
    const int tid = threadIdx.x;
    const int wid = tid >> 6;
    const int lane = tid & 63;
    const int l15 = lane & 15, lg = lane >> 4;
    const unsigned short* Bt; const float* bb; int r0;
    if ((int)blockIdx.x < nb1) { Bt = Bt1; bb = b1a; r0 = blockIdx.x * 64; }
    else { Bt = Bt2; bb = b1b; r0 = np64 + ((int)blockIdx.x - nb1) * 64; }
    const int cbase = wid * 32;
    const int kb = lg * 8;
    f32x4 acc[4][2] = {};
    short8v b0 = *(const short8v*)&Bt[(size_t)(cbase + l15) * 32 + kb];
    short8v b1v = *(const short8v*)&Bt[(size_t)(cbase + 16 + l15) * 32 + kb];
    #pragma unroll
    for (int rt = 0; rt < 4; ++rt) {
        int gr = r0 + rt * 16 + l15;
        short8v a = (gr < ntot) ? *(const short8v*)&A[(size_t)gr * 32 + kb] : zero8();
        acc[rt][0] = __builtin_amdgcn_mfma_f32_16x16x32_bf16(a, b0, acc[rt][0], 0, 0, 0);
        acc[rt][1] = __builtin_amdgcn_mfma_f32_16x16x32_bf16(a, b1v, acc[rt][1], 0, 0, 0);
    }
    float bc0 = bb[cbase + l15], bc1 = bb[cbase + 16 + l15];
    #pragma unroll
    for (int rt = 0; rt < 4; ++rt)
        #pragma unroll
        for (int i = 0; i < 4; ++i) {
            int lr = rt * 16 + lg * 4 + i;
            int gr = r0 + lr;
            float dd16 = (gr < ntot) ? 16.f * dinv[gr] : 0.f;
            stb[lr][cbase + l15]      = enc1(dd16 * fmaxf(acc[rt][0][i] + bc0, 0.f));
            stb[lr][cbase + 16 + l15] = enc1(dd16 * fmaxf(acc[rt][1][i] + bc1, 0.f));
        }
    __syncthreads();
    #pragma unroll
    for (int h = 0; h < 2; ++h) {
        int idx = h * 256 + tid;
        int r = idx >> 3, q = idx & 7;
        int gr = r0 + r;
        if (gr < ntot)
            *(uint4*)&hb8[(size_t)gr * 32 + q * 4] = *(const uint4*)&stb[r][q * 16];
    }
}

// ---------------- layer 2 pull aggregation: fp8 gather, dual-dst per 32-lane group ----------------
__global__ __launch_bounds__(256) void k_agg(
        const uint4* __restrict__ H8, const int* __restrict__ offs,
        const int* __restrict__ deg, const int* __restrict__ csrs,
        const float* __restrict__ dinv,
        int np, int np64, int nm,
        unsigned short* __restrict__ outb) {
    int grp = threadIdx.x >> 5, lane = threadIdx.x & 31;
    int ntot = np64 + nm;
    int g0 = blockIdx.x * 16 + grp * 2;
    int g1 = g0 + 1;
    bool v0 = (g0 < ntot) && ((g0 < np) || (g0 >= np64));
    bool v1 = (g1 < ntot) && ((g1 < np) || (g1 >= np64));
    if (!v0 && !v1) return;
    int q = lane >> 3, l8 = lane & 7;
    f32x2 a0[8], a1[8];
    #pragma unroll
    for (int c = 0; c < 8; ++c) { a0[c].x = 0.f; a0[c].y = 0.f; a1[c].x = 0.f; a1[c].y = 0.f; }
    if (q == 0) {
        if (v0) { uint4 u = H8[(size_t)g0 * 8 + l8]; dec16p(u, a0); }
        if (v1) { uint4 u = H8[(size_t)g1 * 8 + l8]; dec16p(u, a1); }
    }
    int s00 = v0 ? offs[g0] : 0, m0 = v0 ? deg[g0] : 0;
    int s01 = v1 ? offs[g1] : 0, m1 = v1 ? deg[g1] : 0;
    int mmax = m0 > m1 ? m0 : m1;
    for (int c0 = 0; c0 < mmax; c0 += 32) {
        int rem0 = m0 - c0; if (rem0 > 32) rem0 = 32;
        int rem1 = m1 - c0; if (rem1 > 32) rem1 = 32;
        int li0 = lane < rem0 ? lane : (rem0 > 0 ? rem0 - 1 : 0);
        int li1 = lane < rem1 ? lane : (rem1 > 0 ? rem1 - 1 : 0);
        int se0 = csrs[s00 + c0 + li0];   // coalesced; dummy when rem<=0 (unused)
        int se1 = csrs[s01 + c0 + li1];
        int rmax = rem0 > rem1 ? rem0 : rem1;
        int nq = (rmax + 3) >> 2;
        #pragma unroll 4
        for (int j = 0; j < nq; ++j) {
            int idx = j * 4 + q;
            bool act0 = idx < rem0, act1 = idx < rem1;
            int sA = __shfl(se0, act0 ? idx : 0, 32);
            int sB = __shfl(se1, act1 ? idx : 0, 32);
            uint4 uA = H8[(size_t)sA * 8 + l8];   // 8 rows in flight per group
            uint4 uB = H8[(size_t)sB * 8 + l8];
            if (act0) {
                f32x2 v[8]; dec16p(uA, v);
                #pragma unroll
                for (int c = 0; c < 8; ++c) a0[c] += v[c];
            }
            if (act1) {
                f32x2 v[8]; dec16p(uB, v);
                #pragma unroll
                for (int c = 0; c < 8; ++c) a1[c] += v[c];
            }
        }
    }
    #pragma unroll
    for (int c = 0; c < 8; ++c) {
        a0[c].x += __shfl_xor(a0[c].x, 8, 32);
        a0[c].y += __shfl_xor(a0[c].y, 8, 32);
        a0[c].x += __shfl_xor(a0[c].x, 16, 32);
        a0[c].y += __shfl_xor(a0[c].y, 16, 32);
        a1[c].x += __shfl_xor(a1[c].x, 8, 32);
        a1[c].y += __shfl_xor(a1[c].y, 8, 32);
        a1[c].x += __shfl_xor(a1[c].x, 16, 32);
        a1[c].y += __shfl_xor(a1[c].y, 16, 32);
    }
    if (q == 0) {
        if (v0) {
            float di = dinv[g0] * 0.0625f;
            uint4 pk0, pk1;
            pk0.x = f2bf2(di * a0[0].x, di * a0[0].y);
            pk0.y = f2bf2(di * a0[1].x, di * a0[1].y);
            pk0.z = f2bf2(di * a0[2].x, di * a0[2].y);
            pk0.w = f2bf2(di * a0[3].x, di * a0[3].y);
            pk1.x = f2bf2(di * a0[4].x, di * a0[4].y);
            pk1.y = f2bf2(di * a0[5].x, di * a0[5].y);
            pk1.z = f2bf2(di * a0[6].x, di * a0[6].y);
            pk1.w = f2bf2(di * a0[7].x, di * a0[7].y);
            *(uint4*)&outb[(size_t)g0 * HID + l8 * 16]     = pk0;
            *(uint4*)&outb[(size_t)g0 * HID + l8 * 16 + 8] = pk1;
        }
        if (v1) {
            float di = dinv[g1] * 0.0625f;
            uint4 pk0, pk1;
            pk0.x = f2bf2(di * a1[0].x, di * a1[0].y);
            pk0.y = f2bf2(di * a1[1].x, di * a1[1].y);
            pk0.z = f2bf2(di * a1[2].x, di * a1[2].y);
            pk0.w = f2bf2(di * a1[3].x, di * a1[3].y);
            pk1.x = f2bf2(di * a1[4].x, di * a1[4].y);
            pk1.y = f2bf2(di * a1[5].x, di * a1[5].y);
            pk1.z = f2bf2(di * a1[6].x, di * a1[6].y);
            pk1.w = f2bf2(di * a1[7].x, di * a1[7].y);
            *(uint4*)&outb[(size_t)g1 * HID + l8 * 16]     = pk0;
            *(uint4*)&outb[(size_t)g1 * HID + l8 * 16 + 8] = pk1;
        }
    }
}

// ---------------- weight transposes (+ zero bktcnt/done/pool for first run) ----------------
__global__ void k_tr(const float* __restrict__ Wa, const float* __restrict__ Wb,
                     const float* __restrict__ Wc,
                     unsigned short* __restrict__ Ta, unsigned short* __restrict__ Tb,
                     unsigned short* __restrict__ Tc,
                     const float* __restrict__ W1a, const float* __restrict__ W1b,
                     unsigned short* __restrict__ T1a, unsigned short* __restrict__ T1b,
                     int* __restrict__ bktcnt, int* __restrict__ done,
                     float* __restrict__ pool, int pooln) {
    int b = blockIdx.x;
    int k = threadIdx.x;
    if (b == 0) {
        for (int i = k; i < 1024; i += HID) bktcnt[i] = 0;
        if (k == 0) *done = 0;
    } else if (b == 1) {
        for (int i = k; i < pooln; i += HID) pool[i] = 0.f;
    }
    if (b < 384) {
        int col = b & 127, m = b >> 7;
        const float* W = (m == 0) ? Wa : (m == 1 ? Wb : Wc);
        unsigned short* T = (m == 0) ? Ta : (m == 1 ? Tb : Tc);
        T[col * HID + k] = f2bf1(W[k * HID + col]);
    } else {
        int bb = b - 384;
        int col = bb & 127, seg = bb >> 7;
        const float* W = seg ? W1b : W1a;
        unsigned short* T = seg ? T1b : T1a;
        if (k < 32) T[col * 32 + k] = (k < 23) ? f2bf1(W[k * HID + col]) : (unsigned short)0;
    }
}

// ---------------- MFMA bf16 GEMM: C = relu(A @ W + b), bf16 out ----------------
__global__ __launch_bounds__(256) void k_gemm(const unsigned short* __restrict__ A,
        const unsigned short* __restrict__ Bt1, const unsigned short* __restrict__ Bt2,
        const float* __restrict__ b2a, const float* __restrict__ b2b,
        int nb1, int np64, int ntot, unsigned short* __restrict__ C) {
    const int tid = threadIdx.x;
    const int wid = tid >> 6;
    const int lane = tid & 63;
    const int l15 = lane & 15, lg = lane >> 4;
    const unsigned short* Bt; const float* bb; int r0;
    if ((int)blockIdx.x < nb1) { Bt = Bt1; bb = b2a; r0 = blockIdx.x * 64; }
    else { Bt = Bt2; bb = b2b; r0 = np64 + ((int)blockIdx.x - nb1) * 64; }
    const int cbase = wid * 32;
    f32x4 acc[4][2] = {};
    #pragma unroll
    for (int ks = 0; ks < 4; ++ks) {
        int kb = ks * 32 + lg * 8;
        short8v b0 = *(const short8v*)&Bt[(size_t)(cbase + l15) * HID + kb];
        short8v b1 = *(const short8v*)&Bt[(size_t)(cbase + 16 + l15) * HID + kb];
        #pragma unroll
        for (int rt = 0; rt < 4; ++rt) {
            int gr = r0 + rt * 16 + l15;
            short8v a = (gr < ntot) ? *(const short8v*)&A[(size_t)gr * HID + kb] : zero8();
            acc[rt][0] = __builtin_amdgcn_mfma_f32_16x16x32_bf16(a, b0, acc[rt][0], 0, 0, 0);
            acc[rt][1] = __builtin_amdgcn_mfma_f32_16x16x32_bf16(a, b1, acc[rt][1], 0, 0, 0);
        }
    }
    float bc0 = bb[cbase + l15], bc1 = bb[cbase + 16 + l15];
    #pragma unroll
    for (int rt = 0; rt < 4; ++rt)
        #pragma unroll
        for (int i = 0; i < 4; ++i) {
            int gr = r0 + rt * 16 + lg * 4 + i;
            if (gr < ntot) {
                C[(size_t)gr * HID + cbase + l15]      = f2bf1(fmaxf(acc[rt][0][i] + bc0, 0.f));
                C[(size_t)gr * HID + cbase + 16 + l15] = f2bf1(fmaxf(acc[rt][1][i] + bc1, 0.f));
            }
        }
}

// ---------------- mean pool (bf16 input): 64 rows/block ----------------
__global__ void k_pool(const unsigned short* __restrict__ x, const int* __restrict__ batch,
                       float* __restrict__ pool, int* __restrict__ cnt, int n) {
    const int ROWS = 64;
    int start = blockIdx.x * ROWS;
    if (start >= n) return;
    int end = start + ROWS; if (end > n) end = n;
    int c = threadIdx.x;
    float acc = 0.f;
    int cur = batch[start];
    int run = 0;
    for (int r = start; r < end; ++r) {
        int b = batch[r];
        if (b != cur) {
            atomicAdd(&pool[cur * HID + c], acc);
            if (c == 0) atomicAdd(&cnt[cur], run);
            acc = 0.f; run = 0; cur = b;
        }
        acc += bf2f(x[(size_t)r * HID + c]);
        run++;
    }
    atomicAdd(&pool[cur * HID + c], acc);
    if (c == 0) atomicAdd(&cnt[cur], run);
}

// ---------------- pool-div + timestep emb + combo table ----------------
__global__ void k_combo2(const int* __restrict__ t, const float* __restrict__ Wt1,
                         const float* __restrict__ bt1, const float* __restrict__ Wt2,
                         const float* __restrict__ bt2,
                         const float* __restrict__ pool, const int* __restrict__ cntb,
                         const float* __restrict__ Wn1, const float* __restrict__ bn1,
                         float* __restrict__ combo) {
    __shared__ float th[HID];
    __shared__ float pe[HID];
    __shared__ float te[HID];
    int b = blockIdx.x, c = threadIdx.x;
    float tv = (float)t[b];
    float hv = tv * Wt1[c] + bt1[c];
    th[c] = hv > 0.f ? hv : 0.f;
    float dcnt = (float)cntb[b]; if (dcnt < 1.f) dcnt = 1.f;
    pe[c] = pool[b * HID + c] / dcnt;
    __syncthreads();
    float s = bt2[c];
    for (int k = 0; k < HID; ++k) s += th[k] * Wt2[k * HID + c];
    te[c] = s;
    __syncthreads();
    const float* Wp = Wn1 + 128 * HID;
    const float* Wt = Wn1 + 256 * HID;
    float o = bn1[c];
    for (int k = 0; k < HID; ++k)
        o += pe[k] * Wp[k * HID + c] + te[k] * Wt[k * HID + c];
    combo[b * HID + c] = o;
}

// ---------------- fused final head (MFMA GEMM + epilogue + 128x3) ----------------
__global__ __launch_bounds__(256) void k_final(const unsigned short* __restrict__ A,
        const unsigned short* __restrict__ Bt /* Wn1t[0:128] */,
        const float* __restrict__ Wn1, const float* __restrict__ combo,
        const int* __restrict__ mbatch, const float* __restrict__ noisy,
        const float* __restrict__ Wn2, const float* __restrict__ bn2,
        float* __restrict__ out, int n) {
    __shared__ float hsm[64][132];
    const int tid = threadIdx.x;
    const int wid = tid >> 6;
    const int lane = tid & 63;
    const int l15 = lane & 15, lg = lane >> 4;
    const int r0 = blockIdx.x * 64;
    const int cbase = wid * 32;
    f32x4 acc[4][2] = {};
    #pragma unroll
    for (int ks = 0; ks < 4; ++ks) {
        int kb = ks * 32 + lg * 8;
        short8v b0 = *(const short8v*)&Bt[(size_t)(cbase + l15) * HID + kb];
        short8v b1 = *(const short8v*)&Bt[(size_t)(cbase + 16 + l15) * HID + kb];
        #pragma unroll
        for (int rt = 0; rt < 4; ++rt) {
            int gr = r0 + rt * 16 + l15;
            short8v a = (gr < n) ? *(const short8v*)&A[(size_t)gr * HID + kb] : zero8();
            acc[rt][0] = __builtin_amdgcn_mfma_f32_16x16x32_bf16(a, b0, acc[rt][0], 0, 0, 0);
            acc[rt][1] = __builtin_amdgcn_mfma_f32_16x16x32_bf16(a, b1, acc[rt][1], 0, 0, 0);
        }
    }
    const float* Wna = Wn1 + 384 * HID;
    #pragma unroll
    for (int rt = 0; rt < 4; ++rt)
        #pragma unroll
        for (int i = 0; i < 4; ++i) {
            int lr = rt * 16 + lg * 4 + i;
            int gr = r0 + lr;
            if (gr < n) {
                int b = mbatch[gr];
                float na0 = noisy[gr * 3 + 0], na1 = noisy[gr * 3 + 1], na2 = noisy[gr * 3 + 2];
                #pragma unroll
                for (int ct = 0; ct < 2; ++ct) {
                    int col = cbase + ct * 16 + l15;
                    float v = acc[rt][ct][i]
                            + na0 * Wna[col] + na1 * Wna[HID + col] + na2 * Wna[2 * HID + col]
                            + combo[b * HID + col];
                    hsm[lr][col] = v > 0.f ? v : 0.f;
                }
            }
        }
    __syncthreads();
    if (tid < 192) {
        int lr = tid / 3, j = tid - lr * 3;
        int gr = r0 + lr;
        if (gr < n) {
            float s = bn2[j];
            for (int c = 0; c < HID; ++c) s += hsm[lr][c] * Wn2[c * 3 + j];
            out[(size_t)gr * 3 + j] = s;
        }
    }
}

// ---------------- host ----------------
extern "C" void kernel_launch(void* const* d_in, const int* in_sizes, int n_in,
                              void* d_out, int out_size, void* d_ws, size_t ws_size,
                              hipStream_t stream) {
    const int*   p_res  = (const int*)d_in[0];
    const float* p_pos  = (const float*)d_in[1];
    const int*   p_ei   = (const int*)d_in[2];
    const int*   p_bat  = (const int*)d_in[3];
    const int*   m_res  = (const int*)d_in[4];
    const float* m_pos  = (const float*)d_in[5];
    const int*   m_ei   = (const int*)d_in[6];
    const int*   m_bat  = (const int*)d_in[7];
    const int*   t      = (const int*)d_in[8];
    const float* noisy  = (const float*)d_in[9];
    const float* Wp1 = (const float*)d_in[10], *bp1 = (const float*)d_in[11];
    const float* Wp2 = (const float*)d_in[12], *bp2 = (const float*)d_in[13];
    const float* Wm1 = (const float*)d_in[14], *bm1 = (const float*)d_in[15];
    const float* Wm2 = (const float*)d_in[16], *bm2 = (const float*)d_in[17];
    const float* Wt1 = (const float*)d_in[18], *bt1 = (const float*)d_in[19];
    const float* Wt2 = (const float*)d_in[20], *bt2 = (const float*)d_in[21];
    const float* Wn1 = (const float*)d_in[22], *bn1 = (const float*)d_in[23];
    const float* Wn2 = (const float*)d_in[24], *bn2 = (const float*)d_in[25];
    float* out = (float*)d_out;

    const int NP = in_sizes[0];
    const int EP = in_sizes[2] / 2;
    const int NM = in_sizes[4];
    const int EM = in_sizes[6] / 2;
    const int B  = in_sizes[8];
    auto al64 = [](int x) { return (x + 63) & ~63; };

    const int np64 = al64(NP);
    const long ntot_m = (long)np64 + NM;
    const long e2sum = (long)EP + EM;

    auto align256 = [](size_t x) { return (x + 255) & ~(size_t)255; };
    size_t req = 0;
    auto count = [&](size_t nb) { req = align256(req) + nb; };
    count(4ull * ntot_m);            // deg
    count(4ull * ntot_m);            // offs
    count(4ull * ntot_m);            // dinv
    count(16ull * ntot_m);           // nrec
    count(4ull * (1024 + 1025 + 1024 + 1)); // bktcnt + bofs + bcur + done
    count(4ull * e2sum);             // csre (packed int)
    count(4ull * e2sum);             // csrs
    count(1ull * ntot_m * HID);      // hb8 fp8
    count(2ull * ntot_m * HID);      // hb bf16
    count(2ull * ntot_m * HID);      // hc bf16 (also hosts x23 [ntot][32])
    count(2ull * (3 * HID * HID + 2 * HID * 32)); // transposed weights
    count(4ull * (size_t)B * (HID + 1)); // pool + cntb
    count(4ull * (size_t)B * HID);   // combo
    bool merged = ws_size >= req + 4096;

    char* ws = (char*)d_ws;
    size_t off = 0;
    auto alloc = [&](size_t nb) { off = align256(off); size_t r = off; off += nb; return r; };

    const int NMAX = NP > NM ? NP : NM;
    const int EMAXs = EP > EM ? EP : EM;
    const long ntot_a = merged ? ntot_m : (long)al64(NMAX);
    const long etot_a = merged ? e2sum : (long)EMAXs;

    int*   deg  = (int*)(ws + alloc(4ull * ntot_a));
    int*   offs = (int*)(ws + alloc(4ull * ntot_a));
    float* dinv = (float*)(ws + alloc(4ull * ntot_a));
    uint4* nrec = (uint4*)(ws + alloc(16ull * ntot_a));
    int*   bktcnt = (int*)(ws + alloc(4ull * (1024 + 1025 + 1024 + 1)));
    int*   bofs = bktcnt + 1024;
    int*   bcur = bofs + 1025;
    int*   done = bcur + 1024;
    int*   csre = (int*)(ws + alloc(4ull * etot_a));
    int*   csrs = (int*)(ws + alloc(4ull * etot_a));
    unsigned* hb8 = (unsigned*)(ws + alloc(1ull * ntot_a * HID));
    unsigned short* hb = (unsigned short*)(ws + alloc(2ull * ntot_a * HID));
    unsigned short* hc = (unsigned short*)(ws + alloc(2ull * ntot_a * HID));
    unsigned short* x23 = hc;     // [ntot][32] bf16 lives in hc (consumed before hc is written)
    unsigned short* w2ta = (unsigned short*)(ws + alloc(2ull * (3 * HID * HID + 2 * HID * 32)));
    unsigned short* w2tb = w2ta + HID * HID;
    unsigned short* wn1t = w2ta + 2 * HID * HID;
    unsigned short* w1ta = w2ta + 3 * HID * HID;
    unsigned short* w1tb = w1ta + HID * 32;
    float* pool = (float*)(ws + alloc(4ull * (size_t)B * (HID + 1)));
    int*   cntb = (int*)(pool + (size_t)B * HID);
    float* combo = (float*)(ws + alloc(4ull * (size_t)B * HID));

    k_tr<<<640, HID, 0, stream>>>(Wp2, Wm2, Wn1, w2ta, w2tb, wn1t, Wp1, Wm1, w1ta, w1tb,
                                  bktcnt, done, pool, B * (HID + 1));

    auto run = [&](int np_, int nm_,
                   const int* ei1, int e1, const int* ei2, int e2,
                   const int* res1, const float* pos1, const int* res2, const float* pos2,
                   const float* b1a, const float* b1b,
                   const unsigned short* w1A, const unsigned short* w1B,
                   const float* b2a, const float* b2b) {
        const int np64_ = al64(np_);
        const int ntot = np64_ + nm_;
        const long etot = (long)e1 + e2;
        const int nb = (ntot + 127) >> BSH;
        const int* s1 = ei1, *d1 = ei1 + e1;
        const int* s2 = ei2, *d2 = ei2 + e2;
        const int nhb = (int)((etot + HCHUNK - 1) / HCHUNK);
        k_bhist<<<nhb, 256, 0, stream>>>(d1, e1, d2, e2, np64_, bktcnt, bofs, bcur,
                                         done, nhb, etot);
        k_part<<<(int)((etot + PCHUNK - 1) / PCHUNK), 256, 0, stream>>>(
            s1, d1, e1, s2, d2, e2, np64_, bcur, csre, nb, etot);
        k_csr<<<nb, 256, 0, stream>>>(csre, bofs, csrs, deg, offs, dinv,
                                      res1, pos1, res2, pos2, np_, np64_, nrec, ntot,
                                      bktcnt, done);
        k_agg23c<<<(ntot + 7) / 8, 256, 0, stream>>>(nrec, offs, deg, csrs,
                                                     np_, np64_, nm_, x23);
        const int nb1 = np64_ / 64;
        const int nb2 = (nm_ + 63) / 64;
        k_gemm1<<<nb1 + nb2, 256, 0, stream>>>(x23, w1A, w1B, b1a, b1b, dinv,
                                               nb1, np64_, ntot, hb8);
        k_agg<<<(ntot + 15) / 16, 256, 0, stream>>>((const uint4*)hb8, offs, deg, csrs, dinv,
                                                    np_, np64_, nm_, hc);
        k_gemm<<<nb1 + nb2, 256, 0, stream>>>(hc, w2ta, w2tb, b2a, b2b, nb1, np64_, ntot, hb);
    };

    if (merged) {
        run(NP, NM, p_ei, EP, m_ei, EM,
            p_res, p_pos, m_res, m_pos,
            bp1, bm1, w1ta, w1tb, bp2, bm2);
        k_pool<<<(NP + 63) / 64, HID, 0, stream>>>(hb, p_bat, pool, cntb, NP);
        k_combo2<<<B, HID, 0, stream>>>(t, Wt1, bt1, Wt2, bt2, pool, cntb, Wn1, bn1, combo);
        k_final<<<(NM + 63) / 64, 256, 0, stream>>>(hb + (size_t)np64 * HID, wn1t, Wn1, combo,
                                                    m_bat, noisy, Wn2, bn2, out, NM);
    } else {
        run(NP, 0, p_ei, EP, p_ei, 0,
            p_res, p_pos, p_res, p_pos,
            bp1, bp1, w1ta, w1ta, bp2, bp2);
        k_pool<<<(NP + 63) / 64, HID, 0, stream>>>(hb, p_bat, pool, cntb, NP);
        k_combo2<<<B, HID, 0, stream>>>(t, Wt1, bt1, Wt2, bt2, pool, cntb, Wn1, bn1, combo);
        run(0, NM, m_ei, 0, m_ei, EM,
            m_res, m_pos, m_res, m_pos,
            bm1, bm1, w1tb, w1tb, bm2, bm2);
        k_final<<<(NM + 63) / 64, 256, 0, stream>>>(hb, wn1t, Wn1, combo, m_bat, noisy,
                                                    Wn2, bn2, out, NM);
    }
}

// Round 13
// 221.975 us; speedup vs baseline: 1.0262x; 1.0262x over previous
//
#include <hip/hip_runtime.h>
#include <hip/hip_bf16.h>

#define HID 128
#define BSH 7            // bucket = 128 consecutive dst nodes
#define CSRCAP 4096      // per-bucket edge capacity for LDS sort
#define PCHUNK 4096      // edges per partition block
#define HCHUNK 16384     // edges per bucket-hist block

typedef __attribute__((ext_vector_type(8))) short short8v;
typedef __attribute__((ext_vector_type(4))) float f32x4;
typedef __attribute__((ext_vector_type(2))) float f32x2;

#if defined(__has_builtin)
#if __has_builtin(__builtin_amdgcn_cvt_f32_fp8) && __has_builtin(__builtin_amdgcn_cvt_pk_fp8_f32)
#define HAVE_HW_FP8 1
#endif
#if __has_builtin(__builtin_amdgcn_cvt_pk_f32_fp8)
#define HAVE_HW_FP8_PK 1
#endif
#endif

__device__ __forceinline__ float4 f4fma(float a, float4 x, float4 y) {
    y.x += a * x.x; y.y += a * x.y; y.z += a * x.z; y.w += a * x.w; return y;
}
__device__ __forceinline__ unsigned f2bf2(float lo, float hi) {
    unsigned ul = __float_as_uint(lo), uh = __float_as_uint(hi);
    ul = (ul + 0x7FFF + ((ul >> 16) & 1)) >> 16;
    uh = (uh + 0x7FFF + ((uh >> 16) & 1)) & 0xFFFF0000u;
    return ul | uh;
}
__device__ __forceinline__ unsigned short f2bf1(float v) {
    unsigned u = __float_as_uint(v);
    u = (u + 0x7FFF + ((u >> 16) & 1)) >> 16;
    return (unsigned short)u;
}
__device__ __forceinline__ float bflo(unsigned u) { return __uint_as_float(u << 16); }
__device__ __forceinline__ float bfhi(unsigned u) { return __uint_as_float(u & 0xFFFF0000u); }
__device__ __forceinline__ float bf2f(unsigned short b) {
    return __uint_as_float(((unsigned)b) << 16);
}
__device__ __forceinline__ short8v zero8() {
    short8v z = {0, 0, 0, 0, 0, 0, 0, 0};
    return z;
}

// ---- fp8 e4m3 (values >= 0 only) ----
#ifndef HAVE_HW_FP8
__device__ __forceinline__ unsigned fp8enc_pos(float a) {
    if (a >= 448.f) return 0x7Eu;
    if (a < 0.0009765625f) return 0u;
    unsigned b = __float_as_uint(a);
    int e = (int)(b >> 23) - 127;
    if (e >= -6) {
        unsigned r = b + 0x7FFFFu + ((b >> 20) & 1u);
        e = (int)(r >> 23) - 127;
        unsigned m = (r >> 20) & 7u;
        return ((unsigned)(e + 7) << 3) | m;
    } else {
        int m = (int)(a * 512.f + 0.5f);
        return (unsigned)m;
    }
}
__device__ __forceinline__ float fp8dec1(unsigned u7) {
    float fn = __uint_as_float((u7 + 0x3C0u) << 20);
    float fs = (float)u7 * 0.001953125f;
    return u7 >= 8 ? fn : fs;
}
#endif

__device__ __forceinline__ unsigned char enc1(float a) {
#ifdef HAVE_HW_FP8
    return (unsigned char)(__builtin_amdgcn_cvt_pk_fp8_f32(a, 0.f, 0, false) & 0xff);
#else
    return (unsigned char)fp8enc_pos(a);
#endif
}

// decode 16 fp8 -> 8 packed float2
__device__ __forceinline__ void dec16p(uint4 u, f32x2* v) {
#ifdef HAVE_HW_FP8_PK
    v[0] = __builtin_amdgcn_cvt_pk_f32_fp8((int)u.x, false);
    v[1] = __builtin_amdgcn_cvt_pk_f32_fp8((int)u.x, true);
    v[2] = __builtin_amdgcn_cvt_pk_f32_fp8((int)u.y, false);
    v[3] = __builtin_amdgcn_cvt_pk_f32_fp8((int)u.y, true);
    v[4] = __builtin_amdgcn_cvt_pk_f32_fp8((int)u.z, false);
    v[5] = __builtin_amdgcn_cvt_pk_f32_fp8((int)u.z, true);
    v[6] = __builtin_amdgcn_cvt_pk_f32_fp8((int)u.w, false);
    v[7] = __builtin_amdgcn_cvt_pk_f32_fp8((int)u.w, true);
#else
    unsigned w[4] = {u.x, u.y, u.z, u.w};
    #pragma unroll
    for (int k = 0; k < 4; ++k) {
        f32x2 a, b;
        a.x = fp8dec1(w[k] & 0xffu);         a.y = fp8dec1((w[k] >> 8) & 0xffu);
        b.x = fp8dec1((w[k] >> 16) & 0xffu); b.y = fp8dec1(w[k] >> 24);
        v[2 * k] = a; v[2 * k + 1] = b;
    }
#endif
}

// ---------------- bucket histogram + fused scan (last block) ----------------
__global__ __launch_bounds__(256) void k_bhist(const int* __restrict__ d1, int e1,
        const int* __restrict__ d2, int e2, int base2,
        int* __restrict__ bktcnt, int* __restrict__ bofs, int* __restrict__ bcur,
        int* __restrict__ done, int nblocks, long etot) {
    __shared__ int hist[1024];
    __shared__ int ps[256];
    __shared__ int lastflag;
    int tid = threadIdx.x;
    for (int b = tid; b < 1024; b += 256) hist[b] = 0;
    __syncthreads();
    long start = (long)blockIdx.x * HCHUNK;
    long end = start + HCHUNK; if (end > etot) end = etot;
    for (long i = start + tid; i < end; i += 256) {
        int d = (i < e1) ? d1[i] : d2[i - e1] + base2;
        atomicAdd(&hist[d >> BSH], 1);
    }
    __syncthreads();
    for (int b = tid; b < 1024; b += 256)
        if (hist[b]) atomicAdd(&bktcnt[b], hist[b]);
    __threadfence();
    if (tid == 0) lastflag = (atomicAdd(done, 1) == nblocks - 1);
    __syncthreads();
    if (!lastflag) return;
    __threadfence();
    int b4 = tid * 4;
    int h0 = bktcnt[b4], h1 = bktcnt[b4 + 1], h2 = bktcnt[b4 + 2], h3 = bktcnt[b4 + 3];
    int sum = h0 + h1 + h2 + h3;
    ps[tid] = sum; __syncthreads();
    for (int o = 1; o < 256; o <<= 1) {
        int v = (tid >= o) ? ps[tid - o] : 0;
        __syncthreads();
        ps[tid] += v;
        __syncthreads();
    }
    int ex = ps[tid] - sum;
    bofs[b4] = ex; bcur[b4] = ex;
    bofs[b4 + 1] = ex + h0; bcur[b4 + 1] = ex + h0;
    bofs[b4 + 2] = ex + h0 + h1; bcur[b4 + 2] = ex + h0 + h1;
    bofs[b4 + 3] = ex + h0 + h1 + h2; bcur[b4 + 3] = ex + h0 + h1 + h2;
    if (tid == 255) bofs[1024] = ps[255];
}

// ---------------- partition edges into bucket-grouped order (packed src<<7|dloc) ----------------
__global__ __launch_bounds__(256) void k_part(
        const int* __restrict__ s1, const int* __restrict__ d1, int e1,
        const int* __restrict__ s2, const int* __restrict__ d2, int e2, int base2,
        int* __restrict__ bcur, int* __restrict__ pedge, int nb, long etot) {
    __shared__ int hist[1024];
    __shared__ int lofs[1024];
    __shared__ int gb[1024];
    __shared__ int ps[256];
    __shared__ int stage[PCHUNK];
    __shared__ unsigned short sbk[PCHUNK];
    int tid = threadIdx.x;
    long cbase = (long)blockIdx.x * PCHUNK;
    int cnt = (int)((etot - cbase) < PCHUNK ? (etot - cbase) : PCHUNK);
    for (int b = tid; b < 1024; b += 256) hist[b] = 0;
    __syncthreads();
    for (int i = tid; i < cnt; i += 256) {
        long e = cbase + i;
        int d = (e < e1) ? d1[e] : d2[e - e1] + base2;
        atomicAdd(&hist[d >> BSH], 1);
    }
    __syncthreads();
    int h0 = hist[tid * 4], h1 = hist[tid * 4 + 1], h2 = hist[tid * 4 + 2], h3 = hist[tid * 4 + 3];
    int sum = h0 + h1 + h2 + h3;
    ps[tid] = sum; __syncthreads();
    for (int o = 1; o < 256; o <<= 1) {
        int v = (tid >= o) ? ps[tid - o] : 0;
        __syncthreads();
        ps[tid] += v;
        __syncthreads();
    }
    int ex = ps[tid] - sum;
    lofs[tid * 4] = ex; lofs[tid * 4 + 1] = ex + h0;
    lofs[tid * 4 + 2] = ex + h0 + h1; lofs[tid * 4 + 3] = ex + h0 + h1 + h2;
    __syncthreads();
    for (int b = tid; b < nb; b += 256) {
        int c = hist[b];
        gb[b] = c ? atomicAdd(&bcur[b], c) : 0;
    }
    __syncthreads();
    for (int b = tid; b < 1024; b += 256) hist[b] = 0;
    __syncthreads();
    for (int i = tid; i < cnt; i += 256) {
        long e = cbase + i;
        int s, d;
        if (e < e1) { s = s1[e]; d = d1[e]; }
        else { s = s2[e - e1] + base2; d = d2[e - e1] + base2; }
        int b = d >> BSH;
        int p = lofs[b] + atomicAdd(&hist[b], 1);
        stage[p] = (s << BSH) | (d & ((1 << BSH) - 1));
        sbk[p] = (unsigned short)b;
    }
    __syncthreads();
    for (int i = tid; i < cnt; i += 256) {
        int b = sbk[i];
        pedge[gb[b] + (i - lofs[b])] = stage[i];
    }
}

// ---------------- per-bucket sort -> src CSR + deg/offs/dinv + node records ----------------
__global__ __launch_bounds__(256) void k_csr(const int* __restrict__ pe,
        const int* __restrict__ bofs, int* __restrict__ csrs,
        int* __restrict__ deg, int* __restrict__ offs, float* __restrict__ dinv,
        const int* __restrict__ res1, const float* __restrict__ pos1,
        const int* __restrict__ res2, const float* __restrict__ pos2,
        int np, int np64, uint4* __restrict__ nrec, int n,
        int* __restrict__ bktcnt, int* __restrict__ done) {
    __shared__ int lofs2[128];
    __shared__ int lcnt[128];
    __shared__ int lcur[128];
    __shared__ int sc[128];
    __shared__ int ss[CSRCAP];
    int b = blockIdx.x, tid = threadIdx.x;
    int n0 = b << BSH;
    int nn = (n - n0) < 128 ? (n - n0) : 128;
    if (tid < 128) { lcnt[tid] = 0; lcur[tid] = 0; }
    __syncthreads();
    int base = bofs[b], total = bofs[b + 1] - base;
    for (int i = tid; i < total; i += 256)
        atomicAdd(&lcnt[pe[base + i] & ((1 << BSH) - 1)], 1);
    __syncthreads();
    int v = 0;
    if (tid < 128) { v = lcnt[tid]; sc[tid] = v; }
    __syncthreads();
    for (int o = 1; o < 128; o <<= 1) {
        int t = 0;
        if (tid < 128 && tid >= o) t = sc[tid - o];
        __syncthreads();
        if (tid < 128) sc[tid] += t;
        __syncthreads();
    }
    if (tid < 128) lofs2[tid] = sc[tid] - v;
    if (tid < nn) {
        int node = n0 + tid;
        offs[node] = base + sc[tid] - v;
        deg[node] = v;
        float dv = rsqrtf((float)(v + 1)); // +1 self loop
        dinv[node] = dv;
        const int* res = 0; const float* pos = 0; int bseg = 0; bool valid = false;
        if (node < np) { res = res1; pos = pos1; bseg = 0; valid = true; }
        else if (node >= np64) { res = res2; pos = pos2; bseg = np64; valid = true; }
        if (valid) {
            int lg = node - bseg;
            uint4 rr;
            rr.x = __float_as_uint(dv);
            rr.y = (unsigned)res[lg] | ((unsigned)f2bf1(pos[lg * 3 + 0]) << 16);
            rr.z = (unsigned)f2bf1(pos[lg * 3 + 1]) | ((unsigned)f2bf1(pos[lg * 3 + 2]) << 16);
            rr.w = 0;
            nrec[node] = rr;
        }
    }
    __syncthreads();
    if (total <= CSRCAP) {
        for (int i = tid; i < total; i += 256) {
            int e = pe[base + i];
            int ln = e & ((1 << BSH) - 1);
            int pos_ = lofs2[ln] + atomicAdd(&lcur[ln], 1);
            ss[pos_] = e >> BSH;
        }
        __syncthreads();
        for (int i = tid; i < total; i += 256) csrs[base + i] = ss[i];
    } else {
        for (int i = tid; i < total; i += 256) {
            int e = pe[base + i];
            int ln = e & ((1 << BSH) - 1);
            int pos_ = lofs2[ln] + atomicAdd(&lcur[ln], 1);
            csrs[base + pos_] = e >> BSH;
        }
    }
    if (b == 0) {  // re-zero bucket counters for the next run in this call
        for (int i = tid; i < 1024; i += 256) bktcnt[i] = 0;
        if (tid == 0) *done = 0;
    }
}

// ---------------- layer 1: compact 23-dim aggregation, 16 lanes/node ----------------
__global__ __launch_bounds__(256) void k_agg23c(
        const uint4* __restrict__ nrec, const int* __restrict__ offs,
        const int* __restrict__ deg, const int* __restrict__ csrs,
        int np, int np64, int nm, unsigned short* __restrict__ x23) {
    __shared__ float aggL[16][24];
    int grp = threadIdx.x >> 4, lane = threadIdx.x & 15;
    int g = blockIdx.x * 16 + grp;
    int ntot = np64 + nm;
    if (g >= ntot) return;
    bool valid = (g < np) || (g >= np64);
    if (!valid) {
        ((unsigned*)x23)[(size_t)g * 16 + lane] = 0;
        return;
    }
    if (lane < 12) { aggL[grp][lane] = 0.f; aggL[grp][lane + 12] = 0.f; }
    float sx = 0.f, sy = 0.f, sz = 0.f;
    int s0 = offs[g], m = deg[g];
    for (int i = lane; i < m; i += 16) {
        int s = csrs[s0 + i];
        uint4 r = nrec[s];                   // 16B gather, L2-resident
        float dv = __uint_as_float(r.x);
        int rs = (int)(r.y & 0xffffu);
        atomicAdd(&aggL[grp][rs], dv);       // same-wave DS ordering
        sx += dv * bfhi(r.y); sy += dv * bflo(r.z); sz += dv * bfhi(r.z);
    }
    uint4 sr = nrec[g];
    float dd = __uint_as_float(sr.x);
    if (lane == 0) atomicAdd(&aggL[grp][(int)(sr.y & 0xffffu)], dd);
    #pragma unroll
    for (int o = 1; o < 16; o <<= 1) {
        sx += __shfl_xor(sx, o, 16);
        sy += __shfl_xor(sy, o, 16);
        sz += __shfl_xor(sz, o, 16);
    }
    sx += dd * bfhi(sr.y); sy += dd * bflo(sr.z); sz += dd * bfhi(sr.z);
    // write 2 entries per lane: idx = lane and lane+16
    float v0 = (lane < 20) ? aggL[grp][lane] : 0.f;   // lane<16 -> bins 0..15
    int i1 = lane + 16;
    float v1;
    if (i1 < 20) v1 = aggL[grp][i1];
    else if (i1 == 20) v1 = sx;
    else if (i1 == 21) v1 = sy;
    else if (i1 == 22) v1 = sz;
    else v1 = 0.f;
    unsigned pk = ((unsigned)f2bf1(dd * v0)) | (((unsigned)f2bf1(dd * v1)) << 16);
    // layout: x23[g][lane] holds idx=lane (low) — but gemm1 reads linear [g][0..31].
    // Store as two halves: entry 'lane' at [g][lane], entry 'lane+16' at [g][lane+16].
    x23[(size_t)g * 32 + lane]      = f2bf1(dd * v0);
    x23[(size_t)g * 32 + lane + 16] = f2bf1(dd * v1);
    (void)pk;
}

// ---------------- GEMM1 (K=32): hb8 = fp8(16*dinv*relu(x23 @ W1 + b1)) ----------------
__global__ __launch_bounds__(256) void k_gemm1(const unsigned short* __restrict__ A,
        const unsigned short* __restrict__ Bt1, const unsigned short* __restrict__ Bt2,
        const float* __restrict__ b1a, const float* __restrict__ b1b,
        const float* __restrict__ dinv,
        int nb1, int np64, int ntot, unsigned* __restrict__ hb8) {
    __shared__ unsigned char stb[64][144];
    const int tid = threadIdx.x;
    const int wid = tid >> 6;
    const int lane = tid & 63;
    const int l15 = lane & 15, lg = lane >> 4;
    const unsigned short* Bt; const float* bb; int r0;
    if ((int)blockIdx.x < nb1) { Bt = Bt1; bb = b1a; r0 = blockIdx.x * 64; }
    else { Bt = Bt2; bb = b1b; r0 = np64 + ((int)blockIdx.x - nb1) * 64; }
    const int cbase = wid * 32;
    const int kb = lg * 8;
    f32x4 acc[4][2] = {};
    short8v b0 = *(const short8v*)&Bt[(size_t)(cbase + l15) * 32 + kb];
    short8v b1v = *(const short8v*)&Bt[(size_t)(cbase + 16 + l15) * 32 + kb];
    #pragma unroll
    for (int rt = 0; rt < 4; ++rt) {
        int gr = r0 + rt * 16 + l15;
        short8v a = (gr < ntot) ? *(const short8v*)&A[(size_t)gr * 32 + kb] : zero8();
        acc[rt][0] = __builtin_amdgcn_mfma_f32_16x16x32_bf16(a, b0, acc[rt][0], 0, 0, 0);
        acc[rt][1] = __builtin_amdgcn_mfma_f32_16x16x32_bf16(a, b1v, acc[rt][1], 0, 0, 0);
    }
    float bc0 = bb[cbase + l15], bc1 = bb[cbase + 16 + l15];
    #pragma unroll
    for (int rt = 0; rt < 4; ++rt)
        #pragma unroll
        for (int i = 0; i < 4; ++i) {
            int lr = rt * 16 + lg * 4 + i;
            int gr = r0 + lr;
            float dd16 = (gr < ntot) ? 16.f * dinv[gr] : 0.f;
            stb[lr][cbase + l15]      = enc1(dd16 * fmaxf(acc[rt][0][i] + bc0, 0.f));
            stb[lr][cbase + 16 + l15] = enc1(dd16 * fmaxf(acc[rt][1][i] + bc1, 0.f));
        }
    __syncthreads();
    #pragma unroll
    for (int h = 0; h < 2; ++h) {
        int idx = h * 256 + tid;
        int r = idx >> 3, q = idx & 7;
        int gr = r0 + r;
        if (gr < ntot)
            *(uint4*)&hb8[(size_t)gr * 32 + q * 4] = *(const uint4*)&stb[r][q * 16];
    }
}

// ---------------- layer 2 pull aggregation: fp8 gather, 4 edges / instruction ----------------
__global__ __launch_bounds__(256) void k_agg(
        const uint4* __restrict__ H8, const int* __restrict__ offs,
        const int* __restrict__ deg, const int* __restrict__ csrs,
        const float* __restrict__ dinv,
        int np, int np64, int nm,
        unsigned short* __restrict__ outb) {
    int g = blockIdx.x * 8 + (threadIdx.x >> 5);
    if (g >= np && (g < np64 || g >= np64 + nm)) return;
    int lane = threadIdx.x & 31;
    int q = lane >> 3, l8 = lane & 7;
    f32x2 acc2[8];
    if (q == 0) {
        uint4 u = H8[(size_t)g * 8 + l8];
        dec16p(u, acc2);
    } else {
        #pragma unroll
        for (int c = 0; c < 8; ++c) { acc2[c].x = 0.f; acc2[c].y = 0.f; }
    }
    int s0 = offs[g], m = deg[g];
    for (int c0 = 0; c0 < m; c0 += 32) {
        int rem = m - c0; if (rem > 32) rem = 32;
        int li = lane < rem ? lane : rem - 1;
        int se = csrs[s0 + c0 + li];          // one coalesced 128B load per 32 edges
        int nquad = (rem + 3) >> 2;
        #pragma unroll 8
        for (int j = 0; j < nquad; ++j) {
            int idx = j * 4 + q;
            bool act = idx < rem;
            int s = __shfl(se, act ? idx : 0, 32);
            uint4 u = H8[(size_t)s * 8 + l8];  // 4 different rows per wave-instruction
            if (act) {
                f32x2 v[8]; dec16p(u, v);      // 8 cvt_pk
                #pragma unroll
                for (int c = 0; c < 8; ++c) acc2[c] += v[c];  // 8 v_pk_add_f32
            }
        }
    }
    #pragma unroll
    for (int c = 0; c < 8; ++c) {
        acc2[c].x += __shfl_xor(acc2[c].x, 8, 32);
        acc2[c].y += __shfl_xor(acc2[c].y, 8, 32);
        acc2[c].x += __shfl_xor(acc2[c].x, 16, 32);
        acc2[c].y += __shfl_xor(acc2[c].y, 16, 32);
    }
    if (q == 0) {
        float di = dinv[g] * 0.0625f;
        uint4 pk0, pk1;
        pk0.x = f2bf2(di * acc2[0].x, di * acc2[0].y);
        pk0.y = f2bf2(di * acc2[1].x, di * acc2[1].y);
        pk0.z = f2bf2(di * acc2[2].x, di * acc2[2].y);
        pk0.w = f2bf2(di * acc2[3].x, di * acc2[3].y);
        pk1.x = f2bf2(di * acc2[4].x, di * acc2[4].y);
        pk1.y = f2bf2(di * acc2[5].x, di * acc2[5].y);
        pk1.z = f2bf2(di * acc2[6].x, di * acc2[6].y);
        pk1.w = f2bf2(di * acc2[7].x, di * acc2[7].y);
        *(uint4*)&outb[(size_t)g * HID + l8 * 16]     = pk0;
        *(uint4*)&outb[(size_t)g * HID + l8 * 16 + 8] = pk1;
    }
}

// ---------------- weight transposes (+ zero bktcnt/done/pool for first run) ----------------
__global__ void k_tr(const float* __restrict__ Wa, const float* __restrict__ Wb,
                     const float* __restrict__ Wc,
                     unsigned short* __restrict__ Ta, unsigned short* __restrict__ Tb,
                     unsigned short* __restrict__ Tc,
                     const float* __restrict__ W1a, const float* __restrict__ W1b,
                     unsigned short* __restrict__ T1a, unsigned short* __restrict__ T1b,
                     int* __restrict__ bktcnt, int* __restrict__ done,
                     float* __restrict__ pool, int pooln) {
    int b = blockIdx.x;
    int k = threadIdx.x;
    if (b == 0) {
        for (int i = k; i < 1024; i += HID) bktcnt[i] = 0;
        if (k == 0) *done = 0;
    } else if (b == 1) {
        for (int i = k; i < pooln; i += HID) pool[i] = 0.f;
    }
    if (b < 384) {
        int col = b & 127, m = b >> 7;
        const float* W = (m == 0) ? Wa : (m == 1 ? Wb : Wc);
        unsigned short* T = (m == 0) ? Ta : (m == 1 ? Tb : Tc);
        T[col * HID + k] = f2bf1(W[k * HID + col]);
    } else {
        int bb = b - 384;
        int col = bb & 127, seg = bb >> 7;
        const float* W = seg ? W1b : W1a;
        unsigned short* T = seg ? T1b : T1a;
        if (k < 32) T[col * 32 + k] = (k < 23) ? f2bf1(W[k * HID + col]) : (unsigned short)0;
    }
}

// ---------------- MFMA bf16 GEMM: C = relu(A @ W + b), bf16 out ----------------
__global__ __launch_bounds__(256) void k_gemm(const unsigned short* __restrict__ A,
        const unsigned short* __restrict__ Bt1, const unsigned short* __restrict__ Bt2,
        const float* __restrict__ b2a, const float* __restrict__ b2b,
        int nb1, int np64, int ntot, unsigned short* __restrict__ C) {
    const int tid = threadIdx.x;
    const int wid = tid >> 6;
    const int lane = tid & 63;
    const int l15 = lane & 15, lg = lane >> 4;
    const unsigned short* Bt; const float* bb; int r0;
    if ((int)blockIdx.x < nb1) { Bt = Bt1; bb = b2a; r0 = blockIdx.x * 64; }
    else { Bt = Bt2; bb = b2b; r0 = np64 + ((int)blockIdx.x - nb1) * 64; }
    const int cbase = wid * 32;
    f32x4 acc[4][2] = {};
    #pragma unroll
    for (int ks = 0; ks < 4; ++ks) {
        int kb = ks * 32 + lg * 8;
        short8v b0 = *(const short8v*)&Bt[(size_t)(cbase + l15) * HID + kb];
        short8v b1 = *(const short8v*)&Bt[(size_t)(cbase + 16 + l15) * HID + kb];
        #pragma unroll
        for (int rt = 0; rt < 4; ++rt) {
            int gr = r0 + rt * 16 + l15;
            short8v a = (gr < ntot) ? *(const short8v*)&A[(size_t)gr * HID + kb] : zero8();
            acc[rt][0] = __builtin_amdgcn_mfma_f32_16x16x32_bf16(a, b0, acc[rt][0], 0, 0, 0);
            acc[rt][1] = __builtin_amdgcn_mfma_f32_16x16x32_bf16(a, b1, acc[rt][1], 0, 0, 0);
        }
    }
    float bc0 = bb[cbase + l15], bc1 = bb[cbase + 16 + l15];
    #pragma unroll
    for (int rt = 0; rt < 4; ++rt)
        #pragma unroll
        for (int i = 0; i < 4; ++i) {
            int gr = r0 + rt * 16 + lg * 4 + i;
            if (gr < ntot) {
                C[(size_t)gr * HID + cbase + l15]      = f2bf1(fmaxf(acc[rt][0][i] + bc0, 0.f));
                C[(size_t)gr * HID + cbase + 16 + l15] = f2bf1(fmaxf(acc[rt][1][i] + bc1, 0.f));
            }
        }
}

// ---------------- mean pool (bf16 input): 64 rows/block ----------------
__global__ void k_pool(const unsigned short* __restrict__ x, const int* __restrict__ batch,
                       float* __restrict__ pool, int* __restrict__ cnt, int n) {
    const int ROWS = 64;
    int start = blockIdx.x * ROWS;
    if (start >= n) return;
    int end = start + ROWS; if (end > n) end = n;
    int c = threadIdx.x;
    float acc = 0.f;
    int cur = batch[start];
    int run = 0;
    for (int r = start; r < end; ++r) {
        int b = batch[r];
        if (b != cur) {
            atomicAdd(&pool[cur * HID + c], acc);
            if (c == 0) atomicAdd(&cnt[cur], run);
            acc = 0.f; run = 0; cur = b;
        }
        acc += bf2f(x[(size_t)r * HID + c]);
        run++;
    }
    atomicAdd(&pool[cur * HID + c], acc);
    if (c == 0) atomicAdd(&cnt[cur], run);
}

// ---------------- pool-div + timestep emb + combo table ----------------
__global__ void k_combo2(const int* __restrict__ t, const float* __restrict__ Wt1,
                         const float* __restrict__ bt1, const float* __restrict__ Wt2,
                         const float* __restrict__ bt2,
                         const float* __restrict__ pool, const int* __restrict__ cntb,
                         const float* __restrict__ Wn1, const float* __restrict__ bn1,
                         float* __restrict__ combo) {
    __shared__ float th[HID];
    __shared__ float pe[HID];
    __shared__ float te[HID];
    int b = blockIdx.x, c = threadIdx.x;
    float tv = (float)t[b];
    float hv = tv * Wt1[c] + bt1[c];
    th[c] = hv > 0.f ? hv : 0.f;
    float dcnt = (float)cntb[b]; if (dcnt < 1.f) dcnt = 1.f;
    pe[c] = pool[b * HID + c] / dcnt;
    __syncthreads();
    float s = bt2[c];
    for (int k = 0; k < HID; ++k) s += th[k] * Wt2[k * HID + c];
    te[c] = s;
    __syncthreads();
    const float* Wp = Wn1 + 128 * HID;
    const float* Wt = Wn1 + 256 * HID;
    float o = bn1[c];
    for (int k = 0; k < HID; ++k)
        o += pe[k] * Wp[k * HID + c] + te[k] * Wt[k * HID + c];
    combo[b * HID + c] = o;
}

// ---------------- fused final head (MFMA GEMM + epilogue + 128x3) ----------------
__global__ __launch_bounds__(256) void k_final(const unsigned short* __restrict__ A,
        const unsigned short* __restrict__ Bt /* Wn1t[0:128] */,
        const float* __restrict__ Wn1, const float* __restrict__ combo,
        const int* __restrict__ mbatch, const float* __restrict__ noisy,
        const float* __restrict__ Wn2, const float* __restrict__ bn2,
        float* __restrict__ out, int n) {
    __shared__ float hsm[64][132];
    const int tid = threadIdx.x;
    const int wid = tid >> 6;
    const int lane = tid & 63;
    const int l15 = lane & 15, lg = lane >> 4;
    const int r0 = blockIdx.x * 64;
    const int cbase = wid * 32;
    f32x4 acc[4][2] = {};
    #pragma unroll
    for (int ks = 0; ks < 4; ++ks) {
        int kb = ks * 32 + lg * 8;
        short8v b0 = *(const short8v*)&Bt[(size_t)(cbase + l15) * HID + kb];
        short8v b1 = *(const short8v*)&Bt[(size_t)(cbase + 16 + l15) * HID + kb];
        #pragma unroll
        for (int rt = 0; rt < 4; ++rt) {
            int gr = r0 + rt * 16 + l15;
            short8v a = (gr < n) ? *(const short8v*)&A[(size_t)gr * HID + kb] : zero8();
            acc[rt][0] = __builtin_amdgcn_mfma_f32_16x16x32_bf16(a, b0, acc[rt][0], 0, 0, 0);
            acc[rt][1] = __builtin_amdgcn_mfma_f32_16x16x32_bf16(a, b1, acc[rt][1], 0, 0, 0);
        }
    }
    const float* Wna = Wn1 + 384 * HID;
    #pragma unroll
    for (int rt = 0; rt < 4; ++rt)
        #pragma unroll
        for (int i = 0; i < 4; ++i) {
            int lr = rt * 16 + lg * 4 + i;
            int gr = r0 + lr;
            if (gr < n) {
                int b = mbatch[gr];
                float na0 = noisy[gr * 3 + 0], na1 = noisy[gr * 3 + 1], na2 = noisy[gr * 3 + 2];
                #pragma unroll
                for (int ct = 0; ct < 2; ++ct) {
                    int col = cbase + ct * 16 + l15;
                    float v = acc[rt][ct][i]
                            + na0 * Wna[col] + na1 * Wna[HID + col] + na2 * Wna[2 * HID + col]
                            + combo[b * HID + col];
                    hsm[lr][col] = v > 0.f ? v : 0.f;
                }
            }
        }
    __syncthreads();
    if (tid < 192) {
        int lr = tid / 3, j = tid - lr * 3;
        int gr = r0 + lr;
        if (gr < n) {
            float s = bn2[j];
            for (int c = 0; c < HID; ++c) s += hsm[lr][c] * Wn2[c * 3 + j];
            out[(size_t)gr * 3 + j] = s;
        }
    }
}

// ---------------- host ----------------
extern "C" void kernel_launch(void* const* d_in, const int* in_sizes, int n_in,
                              void* d_out, int out_size, void* d_ws, size_t ws_size,
                              hipStream_t stream) {
    const int*   p_res  = (const int*)d_in[0];
    const float* p_pos  = (const float*)d_in[1];
    const int*   p_ei   = (const int*)d_in[2];
    const int*   p_bat  = (const int*)d_in[3];
    const int*   m_res  = (const int*)d_in[4];
    const float* m_pos  = (const float*)d_in[5];
    const int*   m_ei   = (const int*)d_in[6];
    const int*   m_bat  = (const int*)d_in[7];
    const int*   t      = (const int*)d_in[8];
    const float* noisy  = (const float*)d_in[9];
    const float* Wp1 = (const float*)d_in[10], *bp1 = (const float*)d_in[11];
    const float* Wp2 = (const float*)d_in[12], *bp2 = (const float*)d_in[13];
    const float* Wm1 = (const float*)d_in[14], *bm1 = (const float*)d_in[15];
    const float* Wm2 = (const float*)d_in[16], *bm2 = (const float*)d_in[17];
    const float* Wt1 = (const float*)d_in[18], *bt1 = (const float*)d_in[19];
    const float* Wt2 = (const float*)d_in[20], *bt2 = (const float*)d_in[21];
    const float* Wn1 = (const float*)d_in[22], *bn1 = (const float*)d_in[23];
    const float* Wn2 = (const float*)d_in[24], *bn2 = (const float*)d_in[25];
    float* out = (float*)d_out;

    const int NP = in_sizes[0];
    const int EP = in_sizes[2] / 2;
    const int NM = in_sizes[4];
    const int EM = in_sizes[6] / 2;
    const int B  = in_sizes[8];
    auto al64 = [](int x) { return (x + 63) & ~63; };

    const int np64 = al64(NP);
    const long ntot_m = (long)np64 + NM;
    const long e2sum = (long)EP + EM;

    auto align256 = [](size_t x) { return (x + 255) & ~(size_t)255; };
    size_t req = 0;
    auto count = [&](size_t nb) { req = align256(req) + nb; };
    count(4ull * ntot_m);            // deg
    count(4ull * ntot_m);            // offs
    count(4ull * ntot_m);            // dinv
    count(16ull * ntot_m);           // nrec
    count(4ull * (1024 + 1025 + 1024 + 1)); // bktcnt + bofs + bcur + done
    count(4ull * e2sum);             // csre (packed int)
    count(4ull * e2sum);             // csrs
    count(1ull * ntot_m * HID);      // hb8 fp8
    count(2ull * ntot_m * HID);      // hb bf16
    count(2ull * ntot_m * HID);      // hc bf16 (also hosts x23 [ntot][32])
    count(2ull * (3 * HID * HID + 2 * HID * 32)); // transposed weights
    count(4ull * (size_t)B * (HID + 1)); // pool + cntb
    count(4ull * (size_t)B * HID);   // combo
    bool merged = ws_size >= req + 4096;

    char* ws = (char*)d_ws;
    size_t off = 0;
    auto alloc = [&](size_t nb) { off = align256(off); size_t r = off; off += nb; return r; };

    const int NMAX = NP > NM ? NP : NM;
    const int EMAXs = EP > EM ? EP : EM;
    const long ntot_a = merged ? ntot_m : (long)al64(NMAX);
    const long etot_a = merged ? e2sum : (long)EMAXs;

    int*   deg  = (int*)(ws + alloc(4ull * ntot_a));
    int*   offs = (int*)(ws + alloc(4ull * ntot_a));
    float* dinv = (float*)(ws + alloc(4ull * ntot_a));
    uint4* nrec = (uint4*)(ws + alloc(16ull * ntot_a));
    int*   bktcnt = (int*)(ws + alloc(4ull * (1024 + 1025 + 1024 + 1)));
    int*   bofs = bktcnt + 1024;
    int*   bcur = bofs + 1025;
    int*   done = bcur + 1024;
    int*   csre = (int*)(ws + alloc(4ull * etot_a));
    int*   csrs = (int*)(ws + alloc(4ull * etot_a));
    unsigned* hb8 = (unsigned*)(ws + alloc(1ull * ntot_a * HID));
    unsigned short* hb = (unsigned short*)(ws + alloc(2ull * ntot_a * HID));
    unsigned short* hc = (unsigned short*)(ws + alloc(2ull * ntot_a * HID));
    unsigned short* x23 = hc;     // [ntot][32] bf16 lives in hc (consumed before hc is written)
    unsigned short* w2ta = (unsigned short*)(ws + alloc(2ull * (3 * HID * HID + 2 * HID * 32)));
    unsigned short* w2tb = w2ta + HID * HID;
    unsigned short* wn1t = w2ta + 2 * HID * HID;
    unsigned short* w1ta = w2ta + 3 * HID * HID;
    unsigned short* w1tb = w1ta + HID * 32;
    float* pool = (float*)(ws + alloc(4ull * (size_t)B * (HID + 1)));
    int*   cntb = (int*)(pool + (size_t)B * HID);
    float* combo = (float*)(ws + alloc(4ull * (size_t)B * HID));

    k_tr<<<640, HID, 0, stream>>>(Wp2, Wm2, Wn1, w2ta, w2tb, wn1t, Wp1, Wm1, w1ta, w1tb,
                                  bktcnt, done, pool, B * (HID + 1));

    auto run = [&](int np_, int nm_,
                   const int* ei1, int e1, const int* ei2, int e2,
                   const int* res1, const float* pos1, const int* res2, const float* pos2,
                   const float* b1a, const float* b1b,
                   const unsigned short* w1A, const unsigned short* w1B,
                   const float* b2a, const float* b2b) {
        const int np64_ = al64(np_);
        const int ntot = np64_ + nm_;
        const long etot = (long)e1 + e2;
        const int nb = (ntot + 127) >> BSH;
        const int* s1 = ei1, *d1 = ei1 + e1;
        const int* s2 = ei2, *d2 = ei2 + e2;
        const int nhb = (int)((etot + HCHUNK - 1) / HCHUNK);
        k_bhist<<<nhb, 256, 0, stream>>>(d1, e1, d2, e2, np64_, bktcnt, bofs, bcur,
                                         done, nhb, etot);
        k_part<<<(int)((etot + PCHUNK - 1) / PCHUNK), 256, 0, stream>>>(
            s1, d1, e1, s2, d2, e2, np64_, bcur, csre, nb, etot);
        k_csr<<<nb, 256, 0, stream>>>(csre, bofs, csrs, deg, offs, dinv,
                                      res1, pos1, res2, pos2, np_, np64_, nrec, ntot,
                                      bktcnt, done);
        k_agg23c<<<(ntot + 15) / 16, 256, 0, stream>>>(nrec, offs, deg, csrs,
                                                       np_, np64_, nm_, x23);
        const int nb1 = np64_ / 64;
        const int nb2 = (nm_ + 63) / 64;
        k_gemm1<<<nb1 + nb2, 256, 0, stream>>>(x23, w1A, w1B, b1a, b1b, dinv,
                                               nb1, np64_, ntot, hb8);
        k_agg<<<(ntot + 7) / 8, 256, 0, stream>>>((const uint4*)hb8, offs, deg, csrs, dinv,
                                                  np_, np64_, nm_, hc);
        k_gemm<<<nb1 + nb2, 256, 0, stream>>>(hc, w2ta, w2tb, b2a, b2b, nb1, np64_, ntot, hb);
    };

    if (merged) {
        run(NP, NM, p_ei, EP, m_ei, EM,
            p_res, p_pos, m_res, m_pos,
            bp1, bm1, w1ta, w1tb, bp2, bm2);
        k_pool<<<(NP + 63) / 64, HID, 0, stream>>>(hb, p_bat, pool, cntb, NP);
        k_combo2<<<B, HID, 0, stream>>>(t, Wt1, bt1, Wt2, bt2, pool, cntb, Wn1, bn1, combo);
        k_final<<<(NM + 63) / 64, 256, 0, stream>>>(hb + (size_t)np64 * HID, wn1t, Wn1, combo,
                                                    m_bat, noisy, Wn2, bn2, out, NM);
    } else {
        run(NP, 0, p_ei, EP, p_ei, 0,
            p_res, p_pos, p_res, p_pos,
            bp1, bp1, w1ta, w1ta, bp2, bp2);
        k_pool<<<(NP + 63) / 64, HID, 0, stream>>>(hb, p_bat, pool, cntb, NP);
        k_combo2<<<B, HID, 0, stream>>>(t, Wt1, bt1, Wt2, bt2, pool, cntb, Wn1, bn1, combo);
        run(0, NM, m_ei, 0, m_ei, EM,
            m_res, m_pos, m_res, m_pos,
            bm1, bm1, w1tb, w1tb, bm2, bm2);
        k_final<<<(NM + 63) / 64, 256, 0, stream>>>(hb, wn1t, Wn1, combo, m_bat, noisy,
                                                    Wn2, bn2, out, NM);
    }
}